// Round 1
// baseline (915.748 us; speedup 1.0000x reference)
//
#include <hip/hip_runtime.h>
#include <math.h>

#define BATCH   2
#define T_LEN   2048
#define C_DIM   1024
#define NH      16
#define NKV     8
#define HD      64

// ---------------------------------------------------------------------------
// GEMM: C[M,N] = A[M,K] @ B[N,K]^T, all row-major, M%64==0, N%64==0, K%16==0.
// 64x64 block tile, 256 threads, 4x4 micro-tile per thread.
// ---------------------------------------------------------------------------
__global__ __launch_bounds__(256)
void gemm_nt(const float* __restrict__ A, const float* __restrict__ B,
             float* __restrict__ C, int M, int N, int K) {
    __shared__ float As[16][68];   // [kk][row], pad to 68 (16B-aligned rows)
    __shared__ float Bs[16][68];   // [kk][col]
    const int tid = threadIdx.x;
    const int tx = tid & 15;       // col group
    const int ty = tid >> 4;       // row group
    const int row0 = blockIdx.y * 64;
    const int col0 = blockIdx.x * 64;

    float acc[4][4] = {};

    for (int k0 = 0; k0 < K; k0 += 16) {
        #pragma unroll
        for (int l = 0; l < 4; ++l) {
            int idx = tid + l * 256;       // 0..1023
            int kk = idx & 15;
            int r  = idx >> 4;             // 0..63
            As[kk][r] = A[(long)(row0 + r) * K + k0 + kk];
            Bs[kk][r] = B[(long)(col0 + r) * K + k0 + kk];
        }
        __syncthreads();
        #pragma unroll
        for (int kk = 0; kk < 16; ++kk) {
            float4 av = *(const float4*)&As[kk][ty * 4];
            float4 bv = *(const float4*)&Bs[kk][tx * 4];
            float a_[4] = {av.x, av.y, av.z, av.w};
            float b_[4] = {bv.x, bv.y, bv.z, bv.w};
            #pragma unroll
            for (int i = 0; i < 4; ++i)
                #pragma unroll
                for (int j = 0; j < 4; ++j)
                    acc[i][j] = fmaf(a_[i], b_[j], acc[i][j]);
        }
        __syncthreads();
    }

    #pragma unroll
    for (int i = 0; i < 4; ++i) {
        float4 cv = make_float4(acc[i][0], acc[i][1], acc[i][2], acc[i][3]);
        *(float4*)&C[(long)(row0 + ty * 4 + i) * N + col0 + tx * 4] = cv;
    }
}

// ---------------------------------------------------------------------------
// RoPE + RMS-norm + braid dot. One wave (64 lanes) per (b,t,h) vector.
// Only the scalar s = dot(rmsnorm(rope(q)), w_braid) is needed downstream.
// sdot layout: (B, n_heads, T).
// ---------------------------------------------------------------------------
__global__ __launch_bounds__(256)
void rope_norm_dot(const float* __restrict__ qk, const float* __restrict__ cosb,
                   const float* __restrict__ sinb, const float* __restrict__ wb,
                   float* __restrict__ sdot, int n_heads) {
    const int wave = threadIdx.x >> 6;
    const int lane = threadIdx.x & 63;
    const long vec = (long)blockIdx.x * 4 + wave;          // (b*T + t)*n_heads + h
    const long total = (long)BATCH * T_LEN * n_heads;
    if (vec >= total) return;
    const int h  = (int)(vec % n_heads);
    const long bt = vec / n_heads;                         // b*T + t
    const int t  = (int)(bt % T_LEN);
    const int b  = (int)(bt / T_LEN);

    const float* src = qk + bt * (long)(n_heads * HD) + h * HD;
    const int j = lane & 31;
    const float x1 = src[j];
    const float x2 = src[j + 32];
    const float c  = cosb[t * 32 + j];
    const float s  = sinb[t * 32 + j];
    float r = (lane < 32) ? fmaf(x1, c, x2 * s) : fmaf(x2, c, -x1 * s);

    float ss = r * r;
    #pragma unroll
    for (int m = 1; m < 64; m <<= 1) ss += __shfl_xor(ss, m, 64);
    const float scale = rsqrtf(ss * (1.0f / 64.0f) + 1e-6f);
    const float rn = r * scale;

    float dt = rn * wb[lane];
    #pragma unroll
    for (int m = 1; m < 64; m <<= 1) dt += __shfl_xor(dt, m, 64);
    if (lane == 0)
        sdot[((long)b * n_heads + h) * T_LEN + t] = dt;
}

// ---------------------------------------------------------------------------
// Braid attention: y[b,t,h*64+d] = (1/sqrt(T)) * sum_{s<=t} sigmoid(sq+sk)*v[s,d]
// Block = (t-tile of 64, b*NH + h). 256 threads: lane owns d, 4 waves x 16 rows.
// ---------------------------------------------------------------------------
__global__ __launch_bounds__(256)
void braid_attn(const float* __restrict__ sq, const float* __restrict__ sk,
                const float* __restrict__ v, float* __restrict__ y) {
    __shared__ float P[64 * 68];      // [t][s] padded
    __shared__ float Vs[64 * 64];     // [s][d]
    __shared__ float sq_l[64];
    __shared__ float sk_l[64];

    const int bh = blockIdx.y;        // b*NH + h
    const int b  = bh >> 4;
    const int h  = bh & 15;
    const int t0 = blockIdx.x * 64;
    const int tid = threadIdx.x;
    const int d  = tid & 63;
    const int tq = tid >> 6;          // 0..3

    const float* sq_p = sq + (long)bh * T_LEN + t0;
    const float* sk_p = sk + ((long)b * NKV + (h >> 1)) * T_LEN;
    const float* v_p  = v + (long)b * T_LEN * (NKV * HD) + (h >> 1) * HD;

    if (tid < 64) sq_l[tid] = sq_p[tid];

    float acc[16] = {};

    for (int s0 = 0; s0 <= t0; s0 += 64) {
        __syncthreads();
        if (tid < 64) sk_l[tid] = sk_p[s0 + tid];
        #pragma unroll
        for (int l = 0; l < 16; ++l) {
            int idx = tid + l * 256;           // 0..4095
            int s_l = idx >> 6;
            int d_l = idx & 63;
            Vs[idx] = v_p[(long)(s0 + s_l) * (NKV * HD) + d_l];
        }
        __syncthreads();
        #pragma unroll
        for (int l = 0; l < 16; ++l) {
            int idx = tid + l * 256;
            int t_l = idx >> 6;
            int s_l = idx & 63;
            float z = sq_l[t_l] + sk_l[s_l];
            float sg = 1.0f / (1.0f + __expf(-z));
            if (s0 + s_l > t0 + t_l) sg = 0.0f;  // causal
            P[t_l * 68 + s_l] = sg;
        }
        __syncthreads();
        #pragma unroll 4
        for (int s4 = 0; s4 < 16; ++s4) {
            float v0 = Vs[(s4 * 4 + 0) * 64 + d];
            float v1 = Vs[(s4 * 4 + 1) * 64 + d];
            float v2 = Vs[(s4 * 4 + 2) * 64 + d];
            float v3 = Vs[(s4 * 4 + 3) * 64 + d];
            #pragma unroll
            for (int i = 0; i < 16; ++i) {
                const float4 p = *(const float4*)&P[(4 * i + tq) * 68 + s4 * 4];
                acc[i] = fmaf(p.x, v0, fmaf(p.y, v1, fmaf(p.z, v2, fmaf(p.w, v3, acc[i]))));
            }
        }
    }

    const float inv = (float)(1.0 / (45.254833995939045 + 1e-6));
    #pragma unroll
    for (int i = 0; i < 16; ++i) {
        int t = t0 + 4 * i + tq;
        y[((long)b * T_LEN + t) * C_DIM + h * HD + d] = acc[i] * inv;
    }
}

// ---------------------------------------------------------------------------
extern "C" void kernel_launch(void* const* d_in, const int* in_sizes, int n_in,
                              void* d_out, int out_size, void* d_ws, size_t ws_size,
                              hipStream_t stream) {
    const float* x     = (const float*)d_in[0];
    const float* cosb  = (const float*)d_in[1];
    const float* sinb  = (const float*)d_in[2];
    const float* Wq    = (const float*)d_in[3];
    const float* Wk    = (const float*)d_in[4];
    const float* Wv    = (const float*)d_in[5];
    const float* Wproj = (const float*)d_in[6];
    const float* wb    = (const float*)d_in[7];
    float* out = (float*)d_out;

    const long M = (long)BATCH * T_LEN;     // 4096
    float* ws = (float*)d_ws;
    float* q  = ws;                          // 4096*1024
    float* k  = q  + M * 1024;               // 4096*512
    float* v  = k  + M * 512;                // 4096*512
    float* sq = v  + M * 512;                // 2*16*2048
    float* sk = sq + (long)BATCH * NH * T_LEN;   // 2*8*2048
    float* y  = sk + (long)BATCH * NKV * T_LEN;  // 4096*1024

    dim3 blk(256);
    // QKV projections
    gemm_nt<<<dim3(16, 64), blk, 0, stream>>>(x, Wq, q, 4096, 1024, 1024);
    gemm_nt<<<dim3(8,  64), blk, 0, stream>>>(x, Wk, k, 4096,  512, 1024);
    gemm_nt<<<dim3(8,  64), blk, 0, stream>>>(x, Wv, v, 4096,  512, 1024);
    // RoPE + RMS-norm + braid dots
    rope_norm_dot<<<dim3((BATCH * T_LEN * NH) / 4), blk, 0, stream>>>(q, cosb, sinb, wb, sq, NH);
    rope_norm_dot<<<dim3((BATCH * T_LEN * NKV) / 4), blk, 0, stream>>>(k, cosb, sinb, wb, sk, NKV);
    // Sigmoid braid attention
    braid_attn<<<dim3(T_LEN / 64, BATCH * NH), blk, 0, stream>>>(sq, sk, v, y);
    // Output projection
    gemm_nt<<<dim3(16, 64), blk, 0, stream>>>(y, Wproj, out, 4096, 1024, 1024);
}

// Round 2
// 431.806 us; speedup vs baseline: 2.1207x; 2.1207x over previous
//
#include <hip/hip_runtime.h>
#include <math.h>

#define BATCH   2
#define T_LEN   2048
#define C_DIM   1024
#define NH      16
#define NKV     8
#define HD      64

typedef unsigned short u16;
typedef __attribute__((ext_vector_type(8))) short short8;
typedef __attribute__((ext_vector_type(4))) float floatx4;

__device__ __forceinline__ u16 f2bf(float f) {
    union { float f; unsigned u; } v; v.f = f;
    unsigned r = v.u + 0x7FFF + ((v.u >> 16) & 1);   // round-to-nearest-even
    return (u16)(r >> 16);
}

__device__ __forceinline__ void gload_lds16(const u16* g, u16* l) {
    __builtin_amdgcn_global_load_lds(
        (const __attribute__((address_space(1))) void*)g,
        (__attribute__((address_space(3))) void*)l, 16, 0, 0);
}

// ---------------------------------------------------------------------------
// fp32 -> bf16 elementwise convert. n % 1024 == 0.
// ---------------------------------------------------------------------------
__global__ __launch_bounds__(256)
void cvt_f32_bf16(const float* __restrict__ src, u16* __restrict__ dst, long n) {
    long i = ((long)blockIdx.x * 256 + threadIdx.x) * 4;
    if (i >= n) return;
    float4 f = *(const float4*)&src[i];
    ushort4 o;
    o.x = f2bf(f.x); o.y = f2bf(f.y); o.z = f2bf(f.z); o.w = f2bf(f.w);
    *(ushort4*)&dst[i] = o;
}

// ---------------------------------------------------------------------------
// bf16 MFMA GEMM: C[M,N] = A[M,K] @ B[N,K]^T (fp32 out).
// 128x128 block tile, 256 threads = 4 waves (2x2 of 64x64), BK=32,
// global_load_lds width-16 staging (m97 structure). M,N %128==0, K%32==0.
// ---------------------------------------------------------------------------
__global__ __launch_bounds__(256)
void gemm_bf16_nt(const u16* __restrict__ A, const u16* __restrict__ B,
                  float* __restrict__ C, int M, int N, int K) {
    __shared__ u16 As[128 * 32];
    __shared__ u16 Bs[128 * 32];
    const int tid    = threadIdx.x;
    const int lane   = tid & 63;
    const int wave   = tid >> 6;
    const int row_in = lane & 15;
    const int quad   = lane >> 4;
    const int koff   = quad * 8;
    const int rw     = (wave & 1) * 64;
    const int cw     = (wave >> 1) * 64;
    const int row0   = blockIdx.y * 128;
    const int col0   = blockIdx.x * 128;

    floatx4 acc[4][4] = {};

    for (int k0 = 0; k0 < K; k0 += 32) {
        #pragma unroll
        for (int c = 0; c < 2; ++c) {
            const int l  = c * 256 + tid;
            const int r  = l >> 2;
            const int kc = l & 3;
            const int lb = (c * 256 + (wave << 6)) * 8;   // wave-uniform LDS elem base
            gload_lds16(A + (size_t)(row0 + r) * K + k0 + kc * 8, &As[lb]);
            gload_lds16(B + (size_t)(col0 + r) * K + k0 + kc * 8, &Bs[lb]);
        }
        __syncthreads();
        short8 af[4], bf_[4];
        #pragma unroll
        for (int i = 0; i < 4; ++i)
            af[i] = *(const short8*)&As[(rw + 16 * i + row_in) * 32 + koff];
        #pragma unroll
        for (int j = 0; j < 4; ++j)
            bf_[j] = *(const short8*)&Bs[(cw + 16 * j + row_in) * 32 + koff];
        #pragma unroll
        for (int i = 0; i < 4; ++i)
            #pragma unroll
            for (int j = 0; j < 4; ++j)
                acc[i][j] = __builtin_amdgcn_mfma_f32_16x16x32_bf16(af[i], bf_[j], acc[i][j], 0, 0, 0);
        __syncthreads();
    }

    #pragma unroll
    for (int i = 0; i < 4; ++i)
        #pragma unroll
        for (int j = 0; j < 4; ++j)
            #pragma unroll
            for (int r = 0; r < 4; ++r)
                C[(size_t)(row0 + rw + 16 * i + quad * 4 + r) * N + col0 + cw + 16 * j + row_in]
                    = acc[i][j][r];
}

// ---------------------------------------------------------------------------
// RoPE + RMS-norm + braid dot. One wave per (b,t,h) vector; only the scalar
// dot with w_braid survives. sdot layout (B, n_heads, T). row stride param.
// ---------------------------------------------------------------------------
__global__ __launch_bounds__(256)
void rope_norm_dot(const float* __restrict__ qk, const float* __restrict__ cosb,
                   const float* __restrict__ sinb, const float* __restrict__ wb,
                   float* __restrict__ sdot, int n_heads, int stride) {
    const int wave = threadIdx.x >> 6;
    const int lane = threadIdx.x & 63;
    const long vec = (long)blockIdx.x * 4 + wave;
    const long total = (long)BATCH * T_LEN * n_heads;
    if (vec >= total) return;
    const int h  = (int)(vec % n_heads);
    const long bt = vec / n_heads;
    const int t  = (int)(bt % T_LEN);
    const int b  = (int)(bt / T_LEN);

    const float* src = qk + bt * (long)stride + h * HD;
    const int j = lane & 31;
    const float x1 = src[j];
    const float x2 = src[j + 32];
    const float c  = cosb[t * 32 + j];
    const float s  = sinb[t * 32 + j];
    float r = (lane < 32) ? fmaf(x1, c, x2 * s) : fmaf(x2, c, -x1 * s);

    float ss = r * r;
    #pragma unroll
    for (int m = 1; m < 64; m <<= 1) ss += __shfl_xor(ss, m, 64);
    const float scale = rsqrtf(ss * (1.0f / 64.0f) + 1e-6f);

    float dt = r * scale * wb[lane];
    #pragma unroll
    for (int m = 1; m < 64; m <<= 1) dt += __shfl_xor(dt, m, 64);
    if (lane == 0)
        sdot[((long)b * n_heads + h) * T_LEN + t] = dt;
}

// ---------------------------------------------------------------------------
// Braid attention, GEMM-structured: y[t,d] = inv * sum_{s<=t} sig(sq+sk)*v[s,d]
// Block = 64 t-rows x 64 d-cols, 256 threads, 4x4 micro-tile.
// P stored [s][t], V stored [s][d] (pad 68). Reverse t-tile order: biggest
// work first -> kills the causal tail. v rows have stride 1024 (kv buffer).
// Output written as bf16 (feeds proj GEMM).
// ---------------------------------------------------------------------------
__global__ __launch_bounds__(256)
void braid_attn(const float* __restrict__ sq, const float* __restrict__ sk,
                const float* __restrict__ v, u16* __restrict__ yb) {
    __shared__ float Ps[64 * 68];   // [s][t]
    __shared__ float Vs[64 * 68];   // [s][d]

    const int bh = blockIdx.y;           // b*NH + h
    const int b  = bh >> 4;
    const int h  = bh & 15;
    const int t0 = (gridDim.x - 1 - blockIdx.x) * 64;   // longest-running first
    const int tid = threadIdx.x;
    const int tx = tid & 15;             // d group
    const int ty = tid >> 4;             // t group

    const float* sq_p = sq + (long)bh * T_LEN + t0;
    const float* sk_p = sk + ((long)b * NKV + (h >> 1)) * T_LEN;
    const float* v_p  = v + (long)b * T_LEN * 1024 + (h >> 1) * HD;

    const float sq_t = sq_p[tid & 63];   // t = idx&63 constant across staging iters
    float acc[4][4] = {};

    for (int s0 = 0; s0 <= t0; s0 += 64) {
        __syncthreads();
        #pragma unroll
        for (int l = 0; l < 16; ++l) {
            int idx = tid + l * 256;
            int s = idx >> 6;
            int d = idx & 63;
            Vs[s * 68 + d] = v_p[(long)(s0 + s) * 1024 + d];
        }
        #pragma unroll
        for (int l = 0; l < 16; ++l) {
            int idx = tid + l * 256;
            int s = idx >> 6;
            int t = idx & 63;
            float z = sq_t + sk_p[s0 + s];
            float sg = __builtin_amdgcn_rcpf(1.0f + __expf(-z));
            if (s0 + s > t0 + t) sg = 0.0f;
            Ps[s * 68 + t] = sg;
        }
        __syncthreads();
        #pragma unroll 8
        for (int s = 0; s < 64; ++s) {
            const float4 pv = *(const float4*)&Ps[s * 68 + ty * 4];
            const float4 vv = *(const float4*)&Vs[s * 68 + tx * 4];
            const float p_[4] = {pv.x, pv.y, pv.z, pv.w};
            const float v_[4] = {vv.x, vv.y, vv.z, vv.w};
            #pragma unroll
            for (int i = 0; i < 4; ++i)
                #pragma unroll
                for (int j = 0; j < 4; ++j)
                    acc[i][j] = fmaf(p_[i], v_[j], acc[i][j]);
        }
    }

    const float inv = (float)(1.0 / (45.254833995939045 + 1e-6));
    #pragma unroll
    for (int i = 0; i < 4; ++i) {
        const int t = t0 + ty * 4 + i;
        ushort4 o;
        o.x = f2bf(acc[i][0] * inv);
        o.y = f2bf(acc[i][1] * inv);
        o.z = f2bf(acc[i][2] * inv);
        o.w = f2bf(acc[i][3] * inv);
        *(ushort4*)&yb[((long)b * T_LEN + t) * C_DIM + h * HD + tx * 4] = o;
    }
}

// ---------------------------------------------------------------------------
extern "C" void kernel_launch(void* const* d_in, const int* in_sizes, int n_in,
                              void* d_out, int out_size, void* d_ws, size_t ws_size,
                              hipStream_t stream) {
    const float* x     = (const float*)d_in[0];
    const float* cosb  = (const float*)d_in[1];
    const float* sinb  = (const float*)d_in[2];
    const float* Wq    = (const float*)d_in[3];
    const float* Wk    = (const float*)d_in[4];
    const float* Wv    = (const float*)d_in[5];
    const float* Wproj = (const float*)d_in[6];
    const float* wb    = (const float*)d_in[7];
    float* out = (float*)d_out;

    char* w = (char*)d_ws;
    u16* xb    = (u16*)w;  w += (size_t)4096 * 1024 * 2;   // x bf16
    u16* Wqb   = (u16*)w;  w += (size_t)1024 * 1024 * 2;
    u16* Wkvb  = (u16*)w;  w += (size_t)1024 * 1024 * 2;   // [Wk; Wv] concat
    u16* Wpb   = (u16*)w;  w += (size_t)1024 * 1024 * 2;
    u16* yb    = (u16*)w;  w += (size_t)4096 * 1024 * 2;   // braid out bf16
    float* q   = (float*)w; w += (size_t)4096 * 1024 * 4;
    float* kv  = (float*)w; w += (size_t)4096 * 1024 * 4;  // cols 0:512 = k, 512:1024 = v
    float* sq  = (float*)w; w += (size_t)BATCH * NH * T_LEN * 4;
    float* sk  = (float*)w; w += (size_t)BATCH * NKV * T_LEN * 4;

    dim3 blk(256);
    // fp32 -> bf16 conversions
    cvt_f32_bf16<<<4096, blk, 0, stream>>>(x, xb, 4194304);
    cvt_f32_bf16<<<1024, blk, 0, stream>>>(Wq, Wqb, 1048576);
    cvt_f32_bf16<<<512,  blk, 0, stream>>>(Wk, Wkvb, 524288);
    cvt_f32_bf16<<<512,  blk, 0, stream>>>(Wv, Wkvb + 524288, 524288);
    cvt_f32_bf16<<<1024, blk, 0, stream>>>(Wproj, Wpb, 1048576);
    // projections (MFMA)
    gemm_bf16_nt<<<dim3(8, 32), blk, 0, stream>>>(xb, Wqb,  q,  4096, 1024, 1024);
    gemm_bf16_nt<<<dim3(8, 32), blk, 0, stream>>>(xb, Wkvb, kv, 4096, 1024, 1024);
    // RoPE + RMS-norm + braid dots
    rope_norm_dot<<<16384, blk, 0, stream>>>(q,  cosb, sinb, wb, sq, NH,  1024);
    rope_norm_dot<<<8192,  blk, 0, stream>>>(kv, cosb, sinb, wb, sk, NKV, 1024);
    // sigmoid braid attention (v = kv cols 512..1023)
    braid_attn<<<dim3(32, 32), blk, 0, stream>>>(sq, sk, kv + 512, yb);
    // output projection (MFMA)
    gemm_bf16_nt<<<dim3(8, 32), blk, 0, stream>>>(yb, Wpb, out, 4096, 1024, 1024);
}

// Round 3
// 232.706 us; speedup vs baseline: 3.9352x; 1.8556x over previous
//
#include <hip/hip_runtime.h>
#include <math.h>

#define BATCH   2
#define T_LEN   2048
#define C_DIM   1024
#define NH      16
#define NKV     8
#define HD      64

typedef unsigned short u16;
typedef __attribute__((ext_vector_type(8))) short short8;
typedef __attribute__((ext_vector_type(4))) float floatx4;

__device__ __forceinline__ u16 f2bf(float f) {
    union { float f; unsigned u; } v; v.f = f;
    unsigned r = v.u + 0x7FFF + ((v.u >> 16) & 1);   // round-to-nearest-even
    return (u16)(r >> 16);
}

__device__ __forceinline__ void gload_lds16(const u16* g, u16* l) {
    __builtin_amdgcn_global_load_lds(
        (const __attribute__((address_space(1))) void*)g,
        (__attribute__((address_space(3))) void*)l, 16, 0, 0);
}

// ---------------------------------------------------------------------------
// fp32 -> bf16 elementwise convert. n % 1024 == 0.
// ---------------------------------------------------------------------------
__global__ __launch_bounds__(256)
void cvt_f32_bf16(const float* __restrict__ src, u16* __restrict__ dst, long n) {
    long i = ((long)blockIdx.x * 256 + threadIdx.x) * 4;
    if (i >= n) return;
    float4 f = *(const float4*)&src[i];
    ushort4 o;
    o.x = f2bf(f.x); o.y = f2bf(f.y); o.z = f2bf(f.z); o.w = f2bf(f.w);
    *(ushort4*)&dst[i] = o;
}

// ---------------------------------------------------------------------------
// bf16 MFMA GEMM: C[M,N] = A[M,K] @ B[N,K]^T (fp32 out). 128x128 tile,
// 256 threads = 4 waves (2x2 of 64x64), BK=32, global_load_lds staging.
// ---------------------------------------------------------------------------
__global__ __launch_bounds__(256)
void gemm_bf16_nt(const u16* __restrict__ A, const u16* __restrict__ B,
                  float* __restrict__ C, int M, int N, int K) {
    __shared__ u16 As[128 * 32];
    __shared__ u16 Bs[128 * 32];
    const int tid    = threadIdx.x;
    const int lane   = tid & 63;
    const int wave   = tid >> 6;
    const int row_in = lane & 15;
    const int quad   = lane >> 4;
    const int koff   = quad * 8;
    const int rw     = (wave & 1) * 64;
    const int cw     = (wave >> 1) * 64;
    const int row0   = blockIdx.y * 128;
    const int col0   = blockIdx.x * 128;

    floatx4 acc[4][4] = {};

    for (int k0 = 0; k0 < K; k0 += 32) {
        #pragma unroll
        for (int c = 0; c < 2; ++c) {
            const int l  = c * 256 + tid;
            const int r  = l >> 2;
            const int kc = l & 3;
            const int lb = (c * 256 + (wave << 6)) * 8;   // wave-uniform LDS elem base
            gload_lds16(A + (size_t)(row0 + r) * K + k0 + kc * 8, &As[lb]);
            gload_lds16(B + (size_t)(col0 + r) * K + k0 + kc * 8, &Bs[lb]);
        }
        __syncthreads();
        short8 af[4], bf_[4];
        #pragma unroll
        for (int i = 0; i < 4; ++i)
            af[i] = *(const short8*)&As[(rw + 16 * i + row_in) * 32 + koff];
        #pragma unroll
        for (int j = 0; j < 4; ++j)
            bf_[j] = *(const short8*)&Bs[(cw + 16 * j + row_in) * 32 + koff];
        #pragma unroll
        for (int i = 0; i < 4; ++i)
            #pragma unroll
            for (int j = 0; j < 4; ++j)
                acc[i][j] = __builtin_amdgcn_mfma_f32_16x16x32_bf16(af[i], bf_[j], acc[i][j], 0, 0, 0);
        __syncthreads();
    }

    #pragma unroll
    for (int i = 0; i < 4; ++i)
        #pragma unroll
        for (int j = 0; j < 4; ++j)
            #pragma unroll
            for (int r = 0; r < 4; ++r)
                C[(size_t)(row0 + rw + 16 * i + quad * 4 + r) * N + col0 + cw + 16 * j + row_in]
                    = acc[i][j][r];
}

// ---------------------------------------------------------------------------
// RoPE + RMS-norm + braid dot. One wave per (b,t,h) vector.
// ---------------------------------------------------------------------------
__global__ __launch_bounds__(256)
void rope_norm_dot(const float* __restrict__ qk, const float* __restrict__ cosb,
                   const float* __restrict__ sinb, const float* __restrict__ wb,
                   float* __restrict__ sdot, int n_heads, int stride) {
    const int wave = threadIdx.x >> 6;
    const int lane = threadIdx.x & 63;
    const long vec = (long)blockIdx.x * 4 + wave;
    const long total = (long)BATCH * T_LEN * n_heads;
    if (vec >= total) return;
    const int h  = (int)(vec % n_heads);
    const long bt = vec / n_heads;
    const int t  = (int)(bt % T_LEN);
    const int b  = (int)(bt / T_LEN);

    const float* src = qk + bt * (long)stride + h * HD;
    const int j = lane & 31;
    const float x1 = src[j];
    const float x2 = src[j + 32];
    const float c  = cosb[t * 32 + j];
    const float s  = sinb[t * 32 + j];
    float r = (lane < 32) ? fmaf(x1, c, x2 * s) : fmaf(x2, c, -x1 * s);

    float ss = r * r;
    #pragma unroll
    for (int m = 1; m < 64; m <<= 1) ss += __shfl_xor(ss, m, 64);
    const float scale = rsqrtf(ss * (1.0f / 64.0f) + 1e-6f);

    float dt = r * scale * wb[lane];
    #pragma unroll
    for (int m = 1; m < 64; m <<= 1) dt += __shfl_xor(dt, m, 64);
    if (lane == 0)
        sdot[((long)b * n_heads + h) * T_LEN + t] = dt;
}

// ---------------------------------------------------------------------------
// V transpose+convert: kv fp32 cols 512..1023 -> Vt bf16 [b*NKV+kvh][d][T].
// ---------------------------------------------------------------------------
__global__ __launch_bounds__(256)
void vt_convert(const float* __restrict__ kv, u16* __restrict__ Vt) {
    __shared__ float L[64][65];
    const int t0  = blockIdx.x * 64;
    const int bkv = blockIdx.y;            // b*NKV + kvh
    const int b   = bkv >> 3;
    const int kvh = bkv & 7;
    const int tid = threadIdx.x;
    const float* src = kv + ((size_t)b * T_LEN + t0) * 1024 + 512 + kvh * 64;
    #pragma unroll
    for (int l = 0; l < 16; ++l) {
        int idx = tid + l * 256;
        int s = idx >> 6, d = idx & 63;
        L[s][d] = src[(size_t)s * 1024 + d];
    }
    __syncthreads();
    u16* dst = Vt + (size_t)bkv * 64 * T_LEN + t0;
    #pragma unroll
    for (int l = 0; l < 16; ++l) {
        int idx = tid + l * 256;
        int d = idx >> 6, s = idx & 63;
        dst[(size_t)d * T_LEN + s] = f2bf(L[s][d]);
    }
}

// ---------------------------------------------------------------------------
// Braid attention, MFMA: y[t,d] = inv * sum_{s<=t} sigmoid(sq[t]+sk[s]) v[s,d]
// Block = 256 thr = 4 waves; t-tile 64 (wave w owns rows w*16+(lane&15)).
// Triangle pairing: block p does t-tiles p and 31-p -> 33 s-chunks each block.
// P computed directly into A-fragments (bf16); V from Vt via global_load_lds
// with XOR-8 group swizzle (bank-conflict-free b128 fragment reads).
// ---------------------------------------------------------------------------
__global__ __launch_bounds__(256)
void braid_attn(const float* __restrict__ sq, const float* __restrict__ sk,
                const u16* __restrict__ Vt, u16* __restrict__ yb) {
    __shared__ u16 Vd[64 * 64];    // [d][s-group swizzled], no padding (gload)
    __shared__ float skl[64];

    const int bh   = blockIdx.y;       // b*NH + h
    const int b    = bh >> 4;
    const int h    = bh & 15;
    const int p    = blockIdx.x;       // pair index 0..15
    const int tid  = threadIdx.x;
    const int lane = tid & 63;
    const int wave = tid >> 6;
    const int n    = lane & 15;
    const int quad = lane >> 4;

    const float* sq_p = sq + (size_t)bh * T_LEN;
    const float* sk_p = sk + ((size_t)b * NKV + (h >> 1)) * T_LEN;
    const u16*   vt_b = Vt + ((size_t)b * NKV + (h >> 1)) * 64 * T_LEN;
    const float  inv  = (float)(1.0 / (45.254833995939045 + 1e-6));

    #pragma unroll
    for (int ph = 0; ph < 2; ++ph) {
        const int tile = ph ? p : (31 - p);
        const int t0   = tile * 64;
        const float sq_lane = sq_p[t0 + wave * 16 + n];

        floatx4 acc[4] = {};

        for (int s0 = 0; s0 <= t0; s0 += 64) {
            __syncthreads();
            #pragma unroll
            for (int c = 0; c < 2; ++c) {
                const int idx = c * 256 + tid;
                const int r = idx >> 3, g = idx & 7;
                gload_lds16(vt_b + (size_t)r * T_LEN + s0 + ((g ^ (r & 7)) << 3),
                            &Vd[idx * 8]);
            }
            if (tid < 64) skl[tid] = sk_p[s0 + tid];
            __syncthreads();

            const bool diag = (s0 == t0);
            #pragma unroll
            for (int kk = 0; kk < 2; ++kk) {
                const float4 s4a = *(const float4*)&skl[kk * 32 + quad * 8];
                const float4 s4b = *(const float4*)&skl[kk * 32 + quad * 8 + 4];
                const float sv[8] = {s4a.x, s4a.y, s4a.z, s4a.w,
                                     s4b.x, s4b.y, s4b.z, s4b.w};
                short8 af;
                #pragma unroll
                for (int j = 0; j < 8; ++j) {
                    const float z = sq_lane + sv[j];
                    float sg = __builtin_amdgcn_rcpf(1.0f + __expf(-z));
                    if (diag && (kk * 32 + quad * 8 + j) > (wave * 16 + n)) sg = 0.0f;
                    af[j] = (short)f2bf(sg);
                }
                #pragma unroll
                for (int j = 0; j < 4; ++j) {
                    const short8 bfr = *(const short8*)
                        &Vd[(16 * j + n) * 64 + (((kk * 4 + quad) ^ (n & 7)) << 3)];
                    acc[j] = __builtin_amdgcn_mfma_f32_16x16x32_bf16(af, bfr, acc[j], 0, 0, 0);
                }
            }
        }

        #pragma unroll
        for (int j = 0; j < 4; ++j)
            #pragma unroll
            for (int r = 0; r < 4; ++r) {
                const int t = t0 + wave * 16 + quad * 4 + r;
                yb[((size_t)b * T_LEN + t) * C_DIM + h * HD + 16 * j + n]
                    = f2bf(acc[j][r] * inv);
            }
    }
}

// ---------------------------------------------------------------------------
extern "C" void kernel_launch(void* const* d_in, const int* in_sizes, int n_in,
                              void* d_out, int out_size, void* d_ws, size_t ws_size,
                              hipStream_t stream) {
    const float* x     = (const float*)d_in[0];
    const float* cosb  = (const float*)d_in[1];
    const float* sinb  = (const float*)d_in[2];
    const float* Wq    = (const float*)d_in[3];
    const float* Wk    = (const float*)d_in[4];
    const float* Wv    = (const float*)d_in[5];
    const float* Wproj = (const float*)d_in[6];
    const float* wb    = (const float*)d_in[7];
    float* out = (float*)d_out;

    char* w = (char*)d_ws;
    u16* xb    = (u16*)w;  w += (size_t)4096 * 1024 * 2;   // x bf16
    u16* Wqb   = (u16*)w;  w += (size_t)1024 * 1024 * 2;
    u16* Wkvb  = (u16*)w;  w += (size_t)1024 * 1024 * 2;   // [Wk; Wv] concat
    u16* Wpb   = (u16*)w;  w += (size_t)1024 * 1024 * 2;
    u16* yb    = (u16*)w;  w += (size_t)4096 * 1024 * 2;   // braid out bf16
    u16* VtB   = (u16*)w;  w += (size_t)BATCH * NKV * 64 * T_LEN * 2;  // V^T bf16
    float* q   = (float*)w; w += (size_t)4096 * 1024 * 4;
    float* kv  = (float*)w; w += (size_t)4096 * 1024 * 4;  // cols 0:512=k, 512:1024=v
    float* sq  = (float*)w; w += (size_t)BATCH * NH * T_LEN * 4;
    float* sk  = (float*)w; w += (size_t)BATCH * NKV * T_LEN * 4;

    dim3 blk(256);
    // fp32 -> bf16 conversions
    cvt_f32_bf16<<<4096, blk, 0, stream>>>(x, xb, 4194304);
    cvt_f32_bf16<<<1024, blk, 0, stream>>>(Wq, Wqb, 1048576);
    cvt_f32_bf16<<<512,  blk, 0, stream>>>(Wk, Wkvb, 524288);
    cvt_f32_bf16<<<512,  blk, 0, stream>>>(Wv, Wkvb + 524288, 524288);
    cvt_f32_bf16<<<1024, blk, 0, stream>>>(Wproj, Wpb, 1048576);
    // projections (MFMA)
    gemm_bf16_nt<<<dim3(8, 32), blk, 0, stream>>>(xb, Wqb,  q,  4096, 1024, 1024);
    gemm_bf16_nt<<<dim3(8, 32), blk, 0, stream>>>(xb, Wkvb, kv, 4096, 1024, 1024);
    // RoPE + RMS-norm + braid dots
    rope_norm_dot<<<16384, blk, 0, stream>>>(q,  cosb, sinb, wb, sq, NH,  1024);
    rope_norm_dot<<<8192,  blk, 0, stream>>>(kv, cosb, sinb, wb, sk, NKV, 1024);
    // V -> bf16 transposed [bkv][d][s]
    vt_convert<<<dim3(32, 16), blk, 0, stream>>>(kv, VtB);
    // sigmoid braid attention (MFMA, triangle-paired)
    braid_attn<<<dim3(16, 32), blk, 0, stream>>>(sq, sk, VtB, yb);
    // output projection (MFMA)
    gemm_bf16_nt<<<dim3(8, 32), blk, 0, stream>>>(yb, Wpb, out, 4096, 1024, 1024);
}

// Round 4
// 183.933 us; speedup vs baseline: 4.9787x; 1.2652x over previous
//
#include <hip/hip_runtime.h>
#include <math.h>

#define BATCH   2
#define T_LEN   2048
#define C_DIM   1024
#define NH      16
#define NKV     8
#define HD      64

typedef unsigned short u16;
typedef __attribute__((ext_vector_type(8))) short short8;
typedef __attribute__((ext_vector_type(4))) float floatx4;

__device__ __forceinline__ u16 f2bf(float f) {
    union { float f; unsigned u; } v; v.f = f;
    unsigned r = v.u + 0x7FFF + ((v.u >> 16) & 1);   // round-to-nearest-even
    return (u16)(r >> 16);
}

__device__ __forceinline__ void gload_lds16(const u16* g, u16* l) {
    __builtin_amdgcn_global_load_lds(
        (const __attribute__((address_space(1))) void*)g,
        (__attribute__((address_space(3))) void*)l, 16, 0, 0);
}

// ---------------------------------------------------------------------------
// All fp32->bf16 conversions in ONE launch. Segments (in 1024-elt blocks):
// x:4096 | Wq:1024 | Wk:512 | Wv:512 | Wproj:1024  => grid 7168.
// Wq/Wk/Wv land concatenated in Wqkvb (2048 rows x 1024).
// ---------------------------------------------------------------------------
__global__ __launch_bounds__(256)
void cvt_all(const float* __restrict__ x, const float* __restrict__ Wq,
             const float* __restrict__ Wk, const float* __restrict__ Wv,
             const float* __restrict__ Wp, u16* __restrict__ xb,
             u16* __restrict__ Wqkvb, u16* __restrict__ Wpb) {
    const int blk = blockIdx.x;
    const float* src; u16* dst; long off;
    if (blk < 4096)      { src = x;  dst = xb;              off = (long)blk * 1024; }
    else if (blk < 5120) { src = Wq; dst = Wqkvb;           off = (long)(blk - 4096) * 1024; }
    else if (blk < 5632) { src = Wk; dst = Wqkvb + 1048576; off = (long)(blk - 5120) * 1024; }
    else if (blk < 6144) { src = Wv; dst = Wqkvb + 1572864; off = (long)(blk - 5632) * 1024; }
    else                 { src = Wp; dst = Wpb;             off = (long)(blk - 6144) * 1024; }
    const float* s = src + (off - off % 1024);   // keep src segment-relative
    (void)s;
    long i = (long)threadIdx.x * 4;
    float4 f = *(const float4*)&src[off % (1 << 30) == off ? off + i : off + i]; // no-op guard
    f = *(const float4*)&src[off + i];
    ushort4 o;
    o.x = f2bf(f.x); o.y = f2bf(f.y); o.z = f2bf(f.z); o.w = f2bf(f.w);
    *(ushort4*)&dst[off + i] = o;
}

// ---------------------------------------------------------------------------
// bf16 MFMA GEMM: C[M,N] = A[M,K] @ B[N,K]^T (fp32 out). 128x128 tile,
// 256 threads = 4 waves (2x2 of 64x64), BK=32, global_load_lds staging.
// ---------------------------------------------------------------------------
__global__ __launch_bounds__(256)
void gemm_bf16_nt(const u16* __restrict__ A, const u16* __restrict__ B,
                  float* __restrict__ C, int M, int N, int K) {
    __shared__ u16 As[128 * 32];
    __shared__ u16 Bs[128 * 32];
    const int tid    = threadIdx.x;
    const int lane   = tid & 63;
    const int wave   = tid >> 6;
    const int row_in = lane & 15;
    const int quad   = lane >> 4;
    const int koff   = quad * 8;
    const int rw     = (wave & 1) * 64;
    const int cw     = (wave >> 1) * 64;
    const int row0   = blockIdx.y * 128;
    const int col0   = blockIdx.x * 128;

    floatx4 acc[4][4] = {};

    for (int k0 = 0; k0 < K; k0 += 32) {
        #pragma unroll
        for (int c = 0; c < 2; ++c) {
            const int l  = c * 256 + tid;
            const int r  = l >> 2;
            const int kc = l & 3;
            gload_lds16(A + (size_t)(row0 + r) * K + k0 + kc * 8, &As[(size_t)l * 8]);
            gload_lds16(B + (size_t)(col0 + r) * K + k0 + kc * 8, &Bs[(size_t)l * 8]);
        }
        __syncthreads();
        short8 af[4], bf_[4];
        #pragma unroll
        for (int i = 0; i < 4; ++i)
            af[i] = *(const short8*)&As[(rw + 16 * i + row_in) * 32 + koff];
        #pragma unroll
        for (int j = 0; j < 4; ++j)
            bf_[j] = *(const short8*)&Bs[(cw + 16 * j + row_in) * 32 + koff];
        #pragma unroll
        for (int i = 0; i < 4; ++i)
            #pragma unroll
            for (int j = 0; j < 4; ++j)
                acc[i][j] = __builtin_amdgcn_mfma_f32_16x16x32_bf16(af[i], bf_[j], acc[i][j], 0, 0, 0);
        __syncthreads();
    }

    #pragma unroll
    for (int i = 0; i < 4; ++i)
        #pragma unroll
        for (int j = 0; j < 4; ++j)
            #pragma unroll
            for (int r = 0; r < 4; ++r)
                C[(size_t)(row0 + rw + 16 * i + quad * 4 + r) * N + col0 + cw + 16 * j + row_in]
                    = acc[i][j][r];
}

// ---------------------------------------------------------------------------
// 128x64-tile variant (for N=1024 proj: 512 blocks -> 2/CU instead of 1/CU).
// 4 waves as 2 (rows) x 2 (cols of 32). acc 4x2.
// ---------------------------------------------------------------------------
__global__ __launch_bounds__(256)
void gemm_bf16_nt2(const u16* __restrict__ A, const u16* __restrict__ B,
                   float* __restrict__ C, int M, int N, int K) {
    __shared__ u16 As[128 * 32];
    __shared__ u16 Bs[64 * 32];
    const int tid    = threadIdx.x;
    const int lane   = tid & 63;
    const int wave   = tid >> 6;
    const int row_in = lane & 15;
    const int quad   = lane >> 4;
    const int koff   = quad * 8;
    const int rw     = (wave & 1) * 64;
    const int cw     = (wave >> 1) * 32;
    const int row0   = blockIdx.y * 128;
    const int col0   = blockIdx.x * 64;

    floatx4 acc[4][2] = {};

    for (int k0 = 0; k0 < K; k0 += 32) {
        #pragma unroll
        for (int c = 0; c < 2; ++c) {
            const int l  = c * 256 + tid;
            const int r  = l >> 2;
            const int kc = l & 3;
            gload_lds16(A + (size_t)(row0 + r) * K + k0 + kc * 8, &As[(size_t)l * 8]);
        }
        {
            const int r  = tid >> 2;
            const int kc = tid & 3;
            gload_lds16(B + (size_t)(col0 + r) * K + k0 + kc * 8, &Bs[(size_t)tid * 8]);
        }
        __syncthreads();
        short8 af[4], bf_[2];
        #pragma unroll
        for (int i = 0; i < 4; ++i)
            af[i] = *(const short8*)&As[(rw + 16 * i + row_in) * 32 + koff];
        #pragma unroll
        for (int j = 0; j < 2; ++j)
            bf_[j] = *(const short8*)&Bs[(cw + 16 * j + row_in) * 32 + koff];
        #pragma unroll
        for (int i = 0; i < 4; ++i)
            #pragma unroll
            for (int j = 0; j < 2; ++j)
                acc[i][j] = __builtin_amdgcn_mfma_f32_16x16x32_bf16(af[i], bf_[j], acc[i][j], 0, 0, 0);
        __syncthreads();
    }

    #pragma unroll
    for (int i = 0; i < 4; ++i)
        #pragma unroll
        for (int j = 0; j < 2; ++j)
            #pragma unroll
            for (int r = 0; r < 4; ++r)
                C[(size_t)(row0 + rw + 16 * i + quad * 4 + r) * N + col0 + cw + 16 * j + row_in]
                    = acc[i][j][r];
}

// ---------------------------------------------------------------------------
// RoPE + RMS-norm + braid dot, q and k in ONE launch. One wave per vector.
// Vectors [0,65536): q heads; [65536,98304): k heads. Output clamped to +-44
// so the braid kernel's exp-factorization can't overflow.
// ---------------------------------------------------------------------------
__global__ __launch_bounds__(256)
void rope_norm_dot(const float* __restrict__ qkv, const float* __restrict__ cosb,
                   const float* __restrict__ sinb, const float* __restrict__ wb,
                   float* __restrict__ sq, float* __restrict__ sk) {
    const int wave = threadIdx.x >> 6;
    const int lane = threadIdx.x & 63;
    const long vec = (long)blockIdx.x * 4 + wave;
    const float* src; float* dst; int t;
    if (vec < 65536) {
        const int h = (int)(vec & 15);
        const long bt = vec >> 4;
        t = (int)(bt & 2047);
        const int b = (int)(bt >> 11);
        src = qkv + bt * 2048 + h * 64;
        dst = sq + ((long)b * NH + h) * T_LEN + t;
    } else {
        const long vk = vec - 65536;
        const int h = (int)(vk & 7);
        const long bt = vk >> 3;
        t = (int)(bt & 2047);
        const int b = (int)(bt >> 11);
        src = qkv + bt * 2048 + 1024 + h * 64;
        dst = sk + ((long)b * NKV + h) * T_LEN + t;
    }

    const int j = lane & 31;
    const float x1 = src[j];
    const float x2 = src[j + 32];
    const float c  = cosb[t * 32 + j];
    const float s  = sinb[t * 32 + j];
    float r = (lane < 32) ? fmaf(x1, c, x2 * s) : fmaf(x2, c, -x1 * s);

    float ss = r * r;
    #pragma unroll
    for (int m = 1; m < 64; m <<= 1) ss += __shfl_xor(ss, m, 64);
    const float scale = rsqrtf(ss * (1.0f / 64.0f) + 1e-6f);

    float dt = r * scale * wb[lane];
    #pragma unroll
    for (int m = 1; m < 64; m <<= 1) dt += __shfl_xor(dt, m, 64);
    if (lane == 0)
        *dst = fminf(fmaxf(dt, -44.0f), 44.0f);
}

// ---------------------------------------------------------------------------
// V transpose+convert: qkv fp32 cols 1536..2047 -> Vt bf16 [b*NKV+kvh][d][T].
// ---------------------------------------------------------------------------
__global__ __launch_bounds__(256)
void vt_convert(const float* __restrict__ qkv, u16* __restrict__ Vt) {
    __shared__ float L[64][65];
    const int t0  = blockIdx.x * 64;
    const int bkv = blockIdx.y;
    const int b   = bkv >> 3;
    const int kvh = bkv & 7;
    const int tid = threadIdx.x;
    const float* src = qkv + ((size_t)b * T_LEN + t0) * 2048 + 1536 + kvh * 64;
    #pragma unroll
    for (int l = 0; l < 16; ++l) {
        int idx = tid + l * 256;
        int s = idx >> 6, d = idx & 63;
        L[s][d] = src[(size_t)s * 2048 + d];
    }
    __syncthreads();
    u16* dst = Vt + (size_t)bkv * 64 * T_LEN + t0;
    #pragma unroll
    for (int l = 0; l < 16; ++l) {
        int idx = tid + l * 256;
        int d = idx >> 6, s = idx & 63;
        dst[(size_t)d * T_LEN + s] = f2bf(L[s][d]);
    }
}

// ---------------------------------------------------------------------------
// Braid attention, MFMA, 512 threads = 8 waves = 2 s-groups x 4 row-waves.
// sigma(sq+sk) = 1/(1 + e^-sq * e^-sk): e^-sq once/row/phase, e^-sk shared in
// LDS -> inner loop = fma + rcp + perm-pack. Triangle pairing (tiles p, 31-p).
// Groups take alternating 64-wide s-chunks; fp32 LDS reduction at phase end.
// ---------------------------------------------------------------------------
__global__ __launch_bounds__(512)
void braid_attn(const float* __restrict__ sq, const float* __restrict__ sk,
                const u16* __restrict__ Vt, u16* __restrict__ yb) {
    __shared__ u16 Vd[2][4096];     // two V chunks, XOR-8 swizzled (gload layout)
    __shared__ float eskl[128];     // e^-sk for both chunks
    float* red = (float*)&Vd[0][0]; // 16 KB reduction scratch (aliased)

    const int bh   = blockIdx.y;
    const int b    = bh >> 4;
    const int h    = bh & 15;
    const int p    = blockIdx.x;    // pair 0..15
    const int tid  = threadIdx.x;
    const int lane = tid & 63;
    const int wave = tid >> 6;      // 0..7
    const int sg   = wave >> 2;     // s-group
    const int w4   = wave & 3;      // row-wave
    const int n    = lane & 15;
    const int quad = lane >> 4;
    const int row  = w4 * 16 + n;   // t-row within tile

    const float* sq_p = sq + (size_t)bh * T_LEN;
    const float* sk_p = sk + ((size_t)b * NKV + (h >> 1)) * T_LEN;
    const u16*   vt_b = Vt + ((size_t)b * NKV + (h >> 1)) * 64 * T_LEN;
    const float  inv  = (float)(1.0 / (45.254833995939045 + 1e-6));

    for (int ph = 0; ph < 2; ++ph) {
        const int t0 = (ph ? p : (31 - p)) * 64;
        const float a = __expf(-sq_p[t0 + row]);
        const int send = t0 + 64;               // one past last valid s
        floatx4 acc[4] = {};

        for (int s0 = 0; s0 < send; s0 += 128) {
            __syncthreads();
            {   // stage V chunk(s): 512 threads x 16B each per chunk
                const int r = tid >> 3, g = tid & 7;
                const int so = (g ^ (r & 7)) << 3;
                gload_lds16(vt_b + (size_t)r * T_LEN + s0 + so, &Vd[0][(size_t)tid * 8]);
                if (s0 + 64 < send)
                    gload_lds16(vt_b + (size_t)r * T_LEN + s0 + 64 + so, &Vd[1][(size_t)tid * 8]);
            }
            if (tid < 128 && (tid < 64 || s0 + 64 < send))
                eskl[tid] = __expf(-sk_p[s0 + tid]);
            __syncthreads();

            const int s0g = s0 + sg * 64;
            if (s0g < send) {
                const bool diag = (s0g == t0);
                #pragma unroll
                for (int kk = 0; kk < 2; ++kk) {
                    const float* eb = &eskl[sg * 64 + kk * 32 + quad * 8];
                    const float4 e0 = *(const float4*)eb;
                    const float4 e1 = *(const float4*)(eb + 4);
                    const float ev[8] = {e0.x, e0.y, e0.z, e0.w, e1.x, e1.y, e1.z, e1.w};
                    union { unsigned u[4]; short8 s8; } af;
                    #pragma unroll
                    for (int jj = 0; jj < 4; ++jj) {
                        float r0 = __builtin_amdgcn_rcpf(fmaf(ev[2 * jj],     a, 1.0f));
                        float r1 = __builtin_amdgcn_rcpf(fmaf(ev[2 * jj + 1], a, 1.0f));
                        if (diag) {
                            const int s_ = kk * 32 + quad * 8 + 2 * jj;
                            if (s_     > row) r0 = 0.0f;
                            if (s_ + 1 > row) r1 = 0.0f;
                        }
                        af.u[jj] = __builtin_amdgcn_perm(__float_as_uint(r1),
                                                         __float_as_uint(r0), 0x07060302u);
                    }
                    #pragma unroll
                    for (int j = 0; j < 4; ++j) {
                        const short8 bfr = *(const short8*)
                            &Vd[sg][(16 * j + n) * 64 + (((kk * 4 + quad) ^ (n & 7)) << 3)];
                        acc[j] = __builtin_amdgcn_mfma_f32_16x16x32_bf16(af.s8, bfr, acc[j], 0, 0, 0);
                    }
                }
            }
        }

        // cross-group reduction (sg1 -> LDS -> sg0 adds) and bf16 store
        __syncthreads();
        if (sg == 1) {
            #pragma unroll
            for (int j = 0; j < 4; ++j)
                #pragma unroll
                for (int r = 0; r < 4; ++r)
                    red[(j * 4 + r) * 256 + w4 * 64 + lane] = acc[j][r];
        }
        __syncthreads();
        if (sg == 0) {
            #pragma unroll
            for (int j = 0; j < 4; ++j)
                #pragma unroll
                for (int r = 0; r < 4; ++r) {
                    const float o = acc[j][r] + red[(j * 4 + r) * 256 + w4 * 64 + lane];
                    const int t = t0 + w4 * 16 + quad * 4 + r;
                    yb[((size_t)b * T_LEN + t) * C_DIM + h * HD + 16 * j + n] = f2bf(o * inv);
                }
        }
    }
}

// ---------------------------------------------------------------------------
extern "C" void kernel_launch(void* const* d_in, const int* in_sizes, int n_in,
                              void* d_out, int out_size, void* d_ws, size_t ws_size,
                              hipStream_t stream) {
    const float* x     = (const float*)d_in[0];
    const float* cosb  = (const float*)d_in[1];
    const float* sinb  = (const float*)d_in[2];
    const float* Wq    = (const float*)d_in[3];
    const float* Wk    = (const float*)d_in[4];
    const float* Wv    = (const float*)d_in[5];
    const float* Wproj = (const float*)d_in[6];
    const float* wb    = (const float*)d_in[7];
    float* out = (float*)d_out;

    char* w = (char*)d_ws;
    u16* xb     = (u16*)w;  w += (size_t)4096 * 1024 * 2;
    u16* Wqkvb  = (u16*)w;  w += (size_t)2048 * 1024 * 2;   // [Wq; Wk; Wv]
    u16* Wpb    = (u16*)w;  w += (size_t)1024 * 1024 * 2;
    u16* yb     = (u16*)w;  w += (size_t)4096 * 1024 * 2;
    u16* VtB    = (u16*)w;  w += (size_t)BATCH * NKV * 64 * T_LEN * 2;
    float* qkv  = (float*)w; w += (size_t)4096 * 2048 * 4;  // q|k|v fp32
    float* sq   = (float*)w; w += (size_t)BATCH * NH * T_LEN * 4;
    float* sk   = (float*)w; w += (size_t)BATCH * NKV * T_LEN * 4;

    dim3 blk(256);
    cvt_all<<<7168, blk, 0, stream>>>(x, Wq, Wk, Wv, Wproj, xb, Wqkvb, Wpb);
    gemm_bf16_nt<<<dim3(16, 32), blk, 0, stream>>>(xb, Wqkvb, qkv, 4096, 2048, 1024);
    rope_norm_dot<<<24576, blk, 0, stream>>>(qkv, cosb, sinb, wb, sq, sk);
    vt_convert<<<dim3(32, 16), blk, 0, stream>>>(qkv, VtB);
    braid_attn<<<dim3(16, 32), dim3(512), 0, stream>>>(sq, sk, VtB, yb);
    gemm_bf16_nt2<<<dim3(16, 32), blk, 0, stream>>>(yb, Wpb, out, 4096, 1024, 1024);
}

// Round 5
// 180.155 us; speedup vs baseline: 5.0831x; 1.0210x over previous
//
#include <hip/hip_runtime.h>

#define BATCH   2
#define T_LEN   2048
#define C_DIM   1024
#define NH      16
#define NKV     8
#define HD      64

typedef unsigned short u16;
typedef __attribute__((ext_vector_type(8))) short short8;
typedef __attribute__((ext_vector_type(4))) float floatx4;

__device__ __forceinline__ u16 f2bf(float f) {
    union { float f; unsigned u; } v; v.f = f;
    unsigned r = v.u + 0x7FFF + ((v.u >> 16) & 1);   // round-to-nearest-even
    return (u16)(r >> 16);
}

__device__ __forceinline__ float bf2f(u16 b) {
    union { unsigned u; float f; } v; v.u = ((unsigned)b) << 16;
    return v.f;
}

__device__ __forceinline__ void gload_lds16(const u16* g, u16* l) {
    __builtin_amdgcn_global_load_lds(
        (const __attribute__((address_space(1))) void*)g,
        (__attribute__((address_space(3))) void*)l, 16, 0, 0);
}

// ---------------------------------------------------------------------------
// All fp32->bf16 conversions in ONE launch. Segments (1024-elt blocks):
// x:4096 | Wq:1024 | Wk:512 | Wv:512 | Wproj:1024 => grid 7168.
// ---------------------------------------------------------------------------
__global__ __launch_bounds__(256)
void cvt_all(const float* __restrict__ x, const float* __restrict__ Wq,
             const float* __restrict__ Wk, const float* __restrict__ Wv,
             const float* __restrict__ Wp, u16* __restrict__ xb,
             u16* __restrict__ Wqkvb, u16* __restrict__ Wpb) {
    const int blk = blockIdx.x;
    const float* src; u16* dst; long off;
    if (blk < 4096)      { src = x;  dst = xb;              off = (long)blk * 1024; }
    else if (blk < 5120) { src = Wq; dst = Wqkvb;           off = (long)(blk - 4096) * 1024; }
    else if (blk < 5632) { src = Wk; dst = Wqkvb + 1048576; off = (long)(blk - 5120) * 1024; }
    else if (blk < 6144) { src = Wv; dst = Wqkvb + 1572864; off = (long)(blk - 5632) * 1024; }
    else                 { src = Wp; dst = Wpb;             off = (long)(blk - 6144) * 1024; }
    const long i = off + (long)threadIdx.x * 4;
    const float4 f = *(const float4*)&src[i];
    ushort4 o;
    o.x = f2bf(f.x); o.y = f2bf(f.y); o.z = f2bf(f.z); o.w = f2bf(f.w);
    *(ushort4*)&dst[i] = o;
}

// ---------------------------------------------------------------------------
// bf16 MFMA GEMM, bf16 OUT: C[M,N] = A[M,K] @ B[N,K]^T. 128x128 tile,
// 256 threads = 4 waves (2x2 of 64x64), BK=32, global_load_lds staging.
// ---------------------------------------------------------------------------
__global__ __launch_bounds__(256)
void gemm_bf16_nt_b16(const u16* __restrict__ A, const u16* __restrict__ B,
                      u16* __restrict__ C, int M, int N, int K) {
    __shared__ u16 As[128 * 32];
    __shared__ u16 Bs[128 * 32];
    const int tid    = threadIdx.x;
    const int lane   = tid & 63;
    const int wave   = tid >> 6;
    const int row_in = lane & 15;
    const int quad   = lane >> 4;
    const int koff   = quad * 8;
    const int rw     = (wave & 1) * 64;
    const int cw     = (wave >> 1) * 64;
    const int row0   = blockIdx.y * 128;
    const int col0   = blockIdx.x * 128;

    floatx4 acc[4][4] = {};

    for (int k0 = 0; k0 < K; k0 += 32) {
        #pragma unroll
        for (int c = 0; c < 2; ++c) {
            const int l  = c * 256 + tid;
            const int r  = l >> 2;
            const int kc = l & 3;
            gload_lds16(A + (size_t)(row0 + r) * K + k0 + kc * 8, &As[(size_t)l * 8]);
            gload_lds16(B + (size_t)(col0 + r) * K + k0 + kc * 8, &Bs[(size_t)l * 8]);
        }
        __syncthreads();
        short8 af[4], bf_[4];
        #pragma unroll
        for (int i = 0; i < 4; ++i)
            af[i] = *(const short8*)&As[(rw + 16 * i + row_in) * 32 + koff];
        #pragma unroll
        for (int j = 0; j < 4; ++j)
            bf_[j] = *(const short8*)&Bs[(cw + 16 * j + row_in) * 32 + koff];
        #pragma unroll
        for (int i = 0; i < 4; ++i)
            #pragma unroll
            for (int j = 0; j < 4; ++j)
                acc[i][j] = __builtin_amdgcn_mfma_f32_16x16x32_bf16(af[i], bf_[j], acc[i][j], 0, 0, 0);
        __syncthreads();
    }

    #pragma unroll
    for (int i = 0; i < 4; ++i)
        #pragma unroll
        for (int j = 0; j < 4; ++j)
            #pragma unroll
            for (int r = 0; r < 4; ++r)
                C[(size_t)(row0 + rw + 16 * i + quad * 4 + r) * N + col0 + cw + 16 * j + row_in]
                    = f2bf(acc[i][j][r]);
    }

// ---------------------------------------------------------------------------
// 128x64-tile fp32-out GEMM (proj: 512 blocks -> 2/CU). 4 waves 2x2, acc 4x2.
// ---------------------------------------------------------------------------
__global__ __launch_bounds__(256)
void gemm_bf16_nt2(const u16* __restrict__ A, const u16* __restrict__ B,
                   float* __restrict__ C, int M, int N, int K) {
    __shared__ u16 As[128 * 32];
    __shared__ u16 Bs[64 * 32];
    const int tid    = threadIdx.x;
    const int lane   = tid & 63;
    const int wave   = tid >> 6;
    const int row_in = lane & 15;
    const int quad   = lane >> 4;
    const int koff   = quad * 8;
    const int rw     = (wave & 1) * 64;
    const int cw     = (wave >> 1) * 32;
    const int row0   = blockIdx.y * 128;
    const int col0   = blockIdx.x * 64;

    floatx4 acc[4][2] = {};

    for (int k0 = 0; k0 < K; k0 += 32) {
        #pragma unroll
        for (int c = 0; c < 2; ++c) {
            const int l  = c * 256 + tid;
            const int r  = l >> 2;
            const int kc = l & 3;
            gload_lds16(A + (size_t)(row0 + r) * K + k0 + kc * 8, &As[(size_t)l * 8]);
        }
        {
            const int r  = tid >> 2;
            const int kc = tid & 3;
            gload_lds16(B + (size_t)(col0 + r) * K + k0 + kc * 8, &Bs[(size_t)tid * 8]);
        }
        __syncthreads();
        short8 af[4], bf_[2];
        #pragma unroll
        for (int i = 0; i < 4; ++i)
            af[i] = *(const short8*)&As[(rw + 16 * i + row_in) * 32 + koff];
        #pragma unroll
        for (int j = 0; j < 2; ++j)
            bf_[j] = *(const short8*)&Bs[(cw + 16 * j + row_in) * 32 + koff];
        #pragma unroll
        for (int i = 0; i < 4; ++i)
            #pragma unroll
            for (int j = 0; j < 2; ++j)
                acc[i][j] = __builtin_amdgcn_mfma_f32_16x16x32_bf16(af[i], bf_[j], acc[i][j], 0, 0, 0);
        __syncthreads();
    }

    #pragma unroll
    for (int i = 0; i < 4; ++i)
        #pragma unroll
        for (int j = 0; j < 2; ++j)
            #pragma unroll
            for (int r = 0; r < 4; ++r)
                C[(size_t)(row0 + rw + 16 * i + quad * 4 + r) * N + col0 + cw + 16 * j + row_in]
                    = acc[i][j][r];
}

// ---------------------------------------------------------------------------
// Post-QKV fused kernel (reads bf16 qkv):
//  blocks [0,512):    V transpose  -> Vt bf16 [b*NKV+kvh][d][T]
//  blocks [512,...):  RoPE + RMS-norm + braid dot -> esq = e^-sq, esk = e^-sk
// sq/sk clamped to +-44 before exp so products in braid can't overflow fp32.
// ---------------------------------------------------------------------------
__global__ __launch_bounds__(256)
void post_qkv(const u16* __restrict__ qkvb, const float* __restrict__ cosb,
              const float* __restrict__ sinb, const float* __restrict__ wb,
              float* __restrict__ esq, float* __restrict__ esk,
              u16* __restrict__ Vt) {
    __shared__ u16 Lu[64][72];
    const int blk = blockIdx.x;
    const int tid = threadIdx.x;

    if (blk < 512) {   // ---- V transpose: tile (t0..t0+63) x (64 d) ----
        const int bkv = blk >> 5;            // b*NKV + kvh
        const int t0  = (blk & 31) * 64;
        const int b   = bkv >> 3;
        const int kvh = bkv & 7;
        const u16* src = qkvb + ((size_t)b * T_LEN + t0) * 2048 + 1536 + kvh * 64;
        #pragma unroll
        for (int c = 0; c < 2; ++c) {
            const int i = c * 256 + tid;
            const int s = i >> 3, d0 = (i & 7) * 8;
            *(short8*)&Lu[s][d0] = *(const short8*)&src[(size_t)s * 2048 + d0];
        }
        __syncthreads();
        u16* dst = Vt + (size_t)bkv * 64 * T_LEN + t0;
        #pragma unroll
        for (int c = 0; c < 2; ++c) {
            const int i = c * 256 + tid;
            const int d = i >> 3, s0 = (i & 7) * 8;
            short8 o;
            #pragma unroll
            for (int j = 0; j < 8; ++j) o[j] = (short)Lu[s0 + j][d];
            *(short8*)&dst[(size_t)d * T_LEN + s0] = o;
        }
        return;
    }

    // ---- RoPE + RMS-norm + dot ----
    const int wave = tid >> 6;
    const int lane = tid & 63;
    const long vec = (long)(blk - 512) * 4 + wave;   // [0,65536): q; rest: k
    const u16* src; float* dst; int t;
    if (vec < 65536) {
        const int h = (int)(vec & 15);
        const long bt = vec >> 4;
        t = (int)(bt & 2047);
        const int b = (int)(bt >> 11);
        src = qkvb + bt * 2048 + h * 64;
        dst = esq + ((long)b * NH + h) * T_LEN + t;
    } else {
        const long vk = vec - 65536;
        const int h = (int)(vk & 7);
        const long bt = vk >> 3;
        t = (int)(bt & 2047);
        const int b = (int)(bt >> 11);
        src = qkvb + bt * 2048 + 1024 + h * 64;
        dst = esk + ((long)b * NKV + h) * T_LEN + t;
    }

    const float v  = bf2f(src[lane]);            // coalesced 128B/wave
    const float ot = __shfl_xor(v, 32, 64);      // partner half
    const int j = lane & 31;
    const float x1 = (lane < 32) ? v : ot;
    const float x2 = (lane < 32) ? ot : v;
    const float c  = cosb[t * 32 + j];
    const float s  = sinb[t * 32 + j];
    const float r  = (lane < 32) ? fmaf(x1, c, x2 * s) : fmaf(x2, c, -x1 * s);

    float ss = r * r;
    #pragma unroll
    for (int m = 1; m < 64; m <<= 1) ss += __shfl_xor(ss, m, 64);
    const float scale = rsqrtf(ss * (1.0f / 64.0f) + 1e-6f);

    float dt = r * scale * wb[lane];
    #pragma unroll
    for (int m = 1; m < 64; m <<= 1) dt += __shfl_xor(dt, m, 64);
    if (lane == 0)
        *dst = __expf(-fminf(fmaxf(dt, -44.0f), 44.0f));
}

// ---------------------------------------------------------------------------
// Braid attention, MFMA, 512 threads = 2 s-groups x 4 row-waves.
// P = 1/(1 + esq[t]*esk[s]); no transcendentals here (precomputed).
// Triangle pairing (tiles p, 31-p). fp32 LDS cross-group reduction.
// ---------------------------------------------------------------------------
__global__ __launch_bounds__(512)
void braid_attn(const float* __restrict__ esq, const float* __restrict__ esk,
                const u16* __restrict__ Vt, u16* __restrict__ yb) {
    __shared__ u16 Vd[2][4096];     // two V chunks, XOR-8 swizzled (gload layout)
    __shared__ float eskl[128];
    float* red = (float*)&Vd[0][0]; // 16 KB reduction scratch (aliased)

    const int bh   = blockIdx.y;
    const int b    = bh >> 4;
    const int h    = bh & 15;
    const int p    = blockIdx.x;    // pair 0..15
    const int tid  = threadIdx.x;
    const int lane = tid & 63;
    const int wave = tid >> 6;      // 0..7
    const int sg   = wave >> 2;     // s-group
    const int w4   = wave & 3;      // row-wave
    const int n    = lane & 15;
    const int quad = lane >> 4;
    const int row  = w4 * 16 + n;   // t-row within tile

    const float* esq_p = esq + (size_t)bh * T_LEN;
    const float* esk_p = esk + ((size_t)b * NKV + (h >> 1)) * T_LEN;
    const u16*   vt_b  = Vt + ((size_t)b * NKV + (h >> 1)) * 64 * T_LEN;
    const float  inv   = (float)(1.0 / (45.254833995939045 + 1e-6));

    for (int ph = 0; ph < 2; ++ph) {
        const int t0 = (ph ? p : (31 - p)) * 64;
        const float a = esq_p[t0 + row];
        const int send = t0 + 64;
        floatx4 acc[4] = {};

        for (int s0 = 0; s0 < send; s0 += 128) {
            __syncthreads();
            {   // stage V chunk(s): 512 threads x 16B per chunk
                const int r = tid >> 3, g = tid & 7;
                const int so = (g ^ (r & 7)) << 3;
                gload_lds16(vt_b + (size_t)r * T_LEN + s0 + so, &Vd[0][(size_t)tid * 8]);
                if (s0 + 64 < send)
                    gload_lds16(vt_b + (size_t)r * T_LEN + s0 + 64 + so, &Vd[1][(size_t)tid * 8]);
            }
            if (tid < 128 && (tid < 64 || s0 + 64 < send))
                eskl[tid] = esk_p[s0 + tid];
            __syncthreads();

            const int s0g = s0 + sg * 64;
            if (s0g < send) {
                const bool diag = (s0g == t0);
                #pragma unroll
                for (int kk = 0; kk < 2; ++kk) {
                    const float* eb = &eskl[sg * 64 + kk * 32 + quad * 8];
                    const float4 e0 = *(const float4*)eb;
                    const float4 e1 = *(const float4*)(eb + 4);
                    const float ev[8] = {e0.x, e0.y, e0.z, e0.w, e1.x, e1.y, e1.z, e1.w};
                    union { unsigned u[4]; short8 s8; } af;
                    #pragma unroll
                    for (int jj = 0; jj < 4; ++jj) {
                        float r0 = __builtin_amdgcn_rcpf(fmaf(ev[2 * jj],     a, 1.0f));
                        float r1 = __builtin_amdgcn_rcpf(fmaf(ev[2 * jj + 1], a, 1.0f));
                        if (diag) {
                            const int s_ = kk * 32 + quad * 8 + 2 * jj;
                            if (s_     > row) r0 = 0.0f;
                            if (s_ + 1 > row) r1 = 0.0f;
                        }
                        af.u[jj] = __builtin_amdgcn_perm(__float_as_uint(r1),
                                                         __float_as_uint(r0), 0x07060302u);
                    }
                    #pragma unroll
                    for (int j = 0; j < 4; ++j) {
                        const short8 bfr = *(const short8*)
                            &Vd[sg][(16 * j + n) * 64 + (((kk * 4 + quad) ^ (n & 7)) << 3)];
                        acc[j] = __builtin_amdgcn_mfma_f32_16x16x32_bf16(af.s8, bfr, acc[j], 0, 0, 0);
                    }
                }
            }
        }

        __syncthreads();
        if (sg == 1) {
            #pragma unroll
            for (int j = 0; j < 4; ++j)
                #pragma unroll
                for (int r = 0; r < 4; ++r)
                    red[(j * 4 + r) * 256 + w4 * 64 + lane] = acc[j][r];
        }
        __syncthreads();
        if (sg == 0) {
            #pragma unroll
            for (int j = 0; j < 4; ++j)
                #pragma unroll
                for (int r = 0; r < 4; ++r) {
                    const float o = acc[j][r] + red[(j * 4 + r) * 256 + w4 * 64 + lane];
                    const int t = t0 + w4 * 16 + quad * 4 + r;
                    yb[((size_t)b * T_LEN + t) * C_DIM + h * HD + 16 * j + n] = f2bf(o * inv);
                }
        }
    }
}

// ---------------------------------------------------------------------------
extern "C" void kernel_launch(void* const* d_in, const int* in_sizes, int n_in,
                              void* d_out, int out_size, void* d_ws, size_t ws_size,
                              hipStream_t stream) {
    const float* x     = (const float*)d_in[0];
    const float* cosb  = (const float*)d_in[1];
    const float* sinb  = (const float*)d_in[2];
    const float* Wq    = (const float*)d_in[3];
    const float* Wk    = (const float*)d_in[4];
    const float* Wv    = (const float*)d_in[5];
    const float* Wproj = (const float*)d_in[6];
    const float* wb    = (const float*)d_in[7];
    float* out = (float*)d_out;

    char* w = (char*)d_ws;
    u16* xb     = (u16*)w;  w += (size_t)4096 * 1024 * 2;
    u16* Wqkvb  = (u16*)w;  w += (size_t)2048 * 1024 * 2;   // [Wq; Wk; Wv]
    u16* Wpb    = (u16*)w;  w += (size_t)1024 * 1024 * 2;
    u16* qkvb   = (u16*)w;  w += (size_t)4096 * 2048 * 2;   // q|k|v bf16
    u16* yb     = (u16*)w;  w += (size_t)4096 * 1024 * 2;
    u16* VtB    = (u16*)w;  w += (size_t)BATCH * NKV * 64 * T_LEN * 2;
    float* esq  = (float*)w; w += (size_t)BATCH * NH * T_LEN * 4;
    float* esk  = (float*)w; w += (size_t)BATCH * NKV * T_LEN * 4;

    dim3 blk(256);
    cvt_all<<<7168, blk, 0, stream>>>(x, Wq, Wk, Wv, Wproj, xb, Wqkvb, Wpb);
    gemm_bf16_nt_b16<<<dim3(16, 32), blk, 0, stream>>>(xb, Wqkvb, qkvb, 4096, 2048, 1024);
    post_qkv<<<512 + 24576, blk, 0, stream>>>(qkvb, cosb, sinb, wb, esq, esk, VtB);
    braid_attn<<<dim3(16, 32), dim3(512), 0, stream>>>(esq, esk, VtB, yb);
    gemm_bf16_nt2<<<dim3(16, 32), blk, 0, stream>>>(yb, Wpb, out, 4096, 1024, 1024);
}

// Round 6
// 168.089 us; speedup vs baseline: 5.4480x; 1.0718x over previous
//
#include <hip/hip_runtime.h>

#define BATCH   2
#define T_LEN   2048
#define C_DIM   1024
#define NH      16
#define NKV     8
#define HD      64

typedef unsigned short u16;
typedef __attribute__((ext_vector_type(8))) short short8;
typedef __attribute__((ext_vector_type(4))) float floatx4;

__device__ __forceinline__ u16 f2bf(float f) {
    union { float f; unsigned u; } v; v.f = f;
    unsigned r = v.u + 0x7FFF + ((v.u >> 16) & 1);   // round-to-nearest-even
    return (u16)(r >> 16);
}

__device__ __forceinline__ void gload_lds16(const u16* g, u16* l) {
    __builtin_amdgcn_global_load_lds(
        (const __attribute__((address_space(1))) void*)g,
        (__attribute__((address_space(3))) void*)l, 16, 0, 0);
}

// ---------------------------------------------------------------------------
// All fp32->bf16 conversions in ONE launch. Segments (1024-elt blocks):
// x:4096 | Wq:1024 | Wk:512 | Wv:512 | Wproj:1024 => grid 7168.
// ---------------------------------------------------------------------------
__global__ __launch_bounds__(256)
void cvt_all(const float* __restrict__ x, const float* __restrict__ Wq,
             const float* __restrict__ Wk, const float* __restrict__ Wv,
             const float* __restrict__ Wp, u16* __restrict__ xb,
             u16* __restrict__ Wqkvb, u16* __restrict__ Wpb) {
    const int blk = blockIdx.x;
    const float* src; u16* dst; long off;
    if (blk < 4096)      { src = x;  dst = xb;              off = (long)blk * 1024; }
    else if (blk < 5120) { src = Wq; dst = Wqkvb;           off = (long)(blk - 4096) * 1024; }
    else if (blk < 5632) { src = Wk; dst = Wqkvb + 1048576; off = (long)(blk - 5120) * 1024; }
    else if (blk < 6144) { src = Wv; dst = Wqkvb + 1572864; off = (long)(blk - 5632) * 1024; }
    else                 { src = Wp; dst = Wpb;             off = (long)(blk - 6144) * 1024; }
    const long i = off + (long)threadIdx.x * 4;
    const float4 f = *(const float4*)&src[i];
    ushort4 o;
    o.x = f2bf(f.x); o.y = f2bf(f.y); o.z = f2bf(f.z); o.w = f2bf(f.w);
    *(ushort4*)&dst[i] = o;
}

// ---------------------------------------------------------------------------
// Fused QKV GEMM: [q|k|v](4096x2048) = xb(4096x1024) @ Wqkvb(2048x1024)^T.
// 128x128 tile, 4 waves (2x2 of 64x64), BK=32, global_load_lds staging.
// Epilogue (per wave; one wave-tile spans exactly one head's 64 cols):
//   q/k cols:  rope + RMS-norm + braid-dot directly from fp32 accs
//              -> esq = e^-clamp(sq), esk = e^-clamp(sk). No tensor write.
//   v cols:    bf16 write to compact vb (4096 x 512).
// Rope pairing (d, d+32) = (j, j+2) within the SAME lane; norm/dot reduce
// across the 16-lane n-group via shfl_xor(1,2,4,8).
// ---------------------------------------------------------------------------
__global__ __launch_bounds__(256)
void gemm_qkv(const u16* __restrict__ A, const u16* __restrict__ B,
              u16* __restrict__ vb, float* __restrict__ esq,
              float* __restrict__ esk, const float* __restrict__ cosb,
              const float* __restrict__ sinb, const float* __restrict__ wb) {
    const int K = 1024;
    __shared__ u16 As[128 * 32];
    __shared__ u16 Bs[128 * 32];
    const int tid    = threadIdx.x;
    const int lane   = tid & 63;
    const int wave   = tid >> 6;
    const int row_in = lane & 15;
    const int quad   = lane >> 4;
    const int koff   = quad * 8;
    const int rw     = (wave & 1) * 64;
    const int cw     = (wave >> 1) * 64;
    const int row0   = blockIdx.y * 128;
    const int col0   = blockIdx.x * 128;

    floatx4 acc[4][4] = {};

    for (int k0 = 0; k0 < K; k0 += 32) {
        #pragma unroll
        for (int c = 0; c < 2; ++c) {
            const int l  = c * 256 + tid;
            const int r  = l >> 2;
            const int kc = l & 3;
            gload_lds16(A + (size_t)(row0 + r) * K + k0 + kc * 8, &As[(size_t)l * 8]);
            gload_lds16(B + (size_t)(col0 + r) * K + k0 + kc * 8, &Bs[(size_t)l * 8]);
        }
        __syncthreads();
        short8 af[4], bf_[4];
        #pragma unroll
        for (int i = 0; i < 4; ++i)
            af[i] = *(const short8*)&As[(rw + 16 * i + row_in) * 32 + koff];
        #pragma unroll
        for (int j = 0; j < 4; ++j)
            bf_[j] = *(const short8*)&Bs[(cw + 16 * j + row_in) * 32 + koff];
        #pragma unroll
        for (int i = 0; i < 4; ++i)
            #pragma unroll
            for (int j = 0; j < 4; ++j)
                acc[i][j] = __builtin_amdgcn_mfma_f32_16x16x32_bf16(af[i], bf_[j], acc[i][j], 0, 0, 0);
        __syncthreads();
    }

    const int n    = row_in;
    const int cw_g = col0 + cw;          // global col base of this wave's head
    const int rw_g = row0 + rw;          // global row base
    const int ch   = cw_g >> 6;          // head index 0..31 (q:0-15 k:16-23 v:24-31)

    if (ch < 24) {      // ---- q/k: rope + RMS-norm + dot -> e^-s ----
        const float w0 = wb[n], w1 = wb[16 + n], w2 = wb[32 + n], w3 = wb[48 + n];
        #pragma unroll
        for (int i = 0; i < 4; ++i)
            #pragma unroll
            for (int r = 0; r < 4; ++r) {
                const int grow = rw_g + 16 * i + quad * 4 + r;
                const int t = grow & 2047;
                const int b = grow >> 11;
                const float c0 = cosb[t * 32 + n];
                const float c1 = cosb[t * 32 + 16 + n];
                const float s0 = sinb[t * 32 + n];
                const float s1 = sinb[t * 32 + 16 + n];
                const float x0 = acc[i][0][r], x1 = acc[i][1][r];
                const float x2 = acc[i][2][r], x3 = acc[i][3][r];
                const float r0 = fmaf(x0, c0,  x2 * s0);
                const float r1 = fmaf(x1, c1,  x3 * s1);
                const float r2 = fmaf(x2, c0, -x0 * s0);
                const float r3 = fmaf(x3, c1, -x1 * s1);
                float ss = r0 * r0 + r1 * r1 + r2 * r2 + r3 * r3;
                float dt = r0 * w0 + r1 * w1 + r2 * w2 + r3 * w3;
                #pragma unroll
                for (int m = 1; m < 16; m <<= 1) {
                    ss += __shfl_xor(ss, m, 64);
                    dt += __shfl_xor(dt, m, 64);
                }
                const float val = dt * rsqrtf(ss * (1.0f / 64.0f) + 1e-6f);
                const float e = __expf(-fminf(fmaxf(val, -44.0f), 44.0f));
                if (n == 0) {
                    if (ch < 16) esq[((size_t)b * NH + ch) * T_LEN + t] = e;
                    else         esk[((size_t)b * NKV + ch - 16) * T_LEN + t] = e;
                }
            }
    } else {            // ---- v: bf16 write to compact vb (row stride 512) ----
        const int vcol = cw_g - 1536;
        #pragma unroll
        for (int i = 0; i < 4; ++i)
            #pragma unroll
            for (int j = 0; j < 4; ++j)
                #pragma unroll
                for (int r = 0; r < 4; ++r)
                    vb[(size_t)(rw_g + 16 * i + quad * 4 + r) * 512 + vcol + 16 * j + n]
                        = f2bf(acc[i][j][r]);
    }
}

// ---------------------------------------------------------------------------
// V transpose (bf16 -> bf16): vb(4096 x 512) -> Vt [b*NKV+kvh][d][T].
// ---------------------------------------------------------------------------
__global__ __launch_bounds__(256)
void vt_convert(const u16* __restrict__ vb, u16* __restrict__ Vt) {
    __shared__ u16 Lu[64][72];
    const int blk = blockIdx.x;
    const int tid = threadIdx.x;
    const int bkv = blk >> 5;            // b*NKV + kvh
    const int t0  = (blk & 31) * 64;
    const int b   = bkv >> 3;
    const int kvh = bkv & 7;
    const u16* src = vb + ((size_t)b * T_LEN + t0) * 512 + kvh * 64;
    #pragma unroll
    for (int c = 0; c < 2; ++c) {
        const int i = c * 256 + tid;
        const int s = i >> 3, d0 = (i & 7) * 8;
        *(short8*)&Lu[s][d0] = *(const short8*)&src[(size_t)s * 512 + d0];
    }
    __syncthreads();
    u16* dst = Vt + (size_t)bkv * 64 * T_LEN + t0;
    #pragma unroll
    for (int c = 0; c < 2; ++c) {
        const int i = c * 256 + tid;
        const int d = i >> 3, s0 = (i & 7) * 8;
        short8 o;
        #pragma unroll
        for (int j = 0; j < 8; ++j) o[j] = (short)Lu[s0 + j][d];
        *(short8*)&dst[(size_t)d * T_LEN + s0] = o;
    }
}

// ---------------------------------------------------------------------------
// Braid attention, MFMA, 512 threads = 2 s-groups x 4 row-waves.
// P = 1/(1 + esq[t]*esk[s]); no transcendentals (precomputed).
// Triangle pairing (tiles p, 31-p). fp32 LDS cross-group reduction.
// ---------------------------------------------------------------------------
__global__ __launch_bounds__(512)
void braid_attn(const float* __restrict__ esq, const float* __restrict__ esk,
                const u16* __restrict__ Vt, u16* __restrict__ yb) {
    __shared__ u16 Vd[2][4096];     // two V chunks, XOR-8 swizzled (gload layout)
    __shared__ float eskl[128];
    float* red = (float*)&Vd[0][0]; // 16 KB reduction scratch (aliased)

    const int bh   = blockIdx.y;
    const int b    = bh >> 4;
    const int h    = bh & 15;
    const int p    = blockIdx.x;    // pair 0..15
    const int tid  = threadIdx.x;
    const int lane = tid & 63;
    const int wave = tid >> 6;      // 0..7
    const int sg   = wave >> 2;     // s-group
    const int w4   = wave & 3;      // row-wave
    const int n    = lane & 15;
    const int quad = lane >> 4;
    const int row  = w4 * 16 + n;   // t-row within tile

    const float* esq_p = esq + (size_t)bh * T_LEN;
    const float* esk_p = esk + ((size_t)b * NKV + (h >> 1)) * T_LEN;
    const u16*   vt_b  = Vt + ((size_t)b * NKV + (h >> 1)) * 64 * T_LEN;
    const float  inv   = (float)(1.0 / (45.254833995939045 + 1e-6));

    for (int ph = 0; ph < 2; ++ph) {
        const int t0 = (ph ? p : (31 - p)) * 64;
        const float a = esq_p[t0 + row];
        const int send = t0 + 64;
        floatx4 acc[4] = {};

        for (int s0 = 0; s0 < send; s0 += 128) {
            __syncthreads();
            {   // stage V chunk(s): 512 threads x 16B per chunk
                const int r = tid >> 3, g = tid & 7;
                const int so = (g ^ (r & 7)) << 3;
                gload_lds16(vt_b + (size_t)r * T_LEN + s0 + so, &Vd[0][(size_t)tid * 8]);
                if (s0 + 64 < send)
                    gload_lds16(vt_b + (size_t)r * T_LEN + s0 + 64 + so, &Vd[1][(size_t)tid * 8]);
            }
            if (tid < 128 && (tid < 64 || s0 + 64 < send))
                eskl[tid] = esk_p[s0 + tid];
            __syncthreads();

            const int s0g = s0 + sg * 64;
            if (s0g < send) {
                const bool diag = (s0g == t0);
                #pragma unroll
                for (int kk = 0; kk < 2; ++kk) {
                    const float* eb = &eskl[sg * 64 + kk * 32 + quad * 8];
                    const float4 e0 = *(const float4*)eb;
                    const float4 e1 = *(const float4*)(eb + 4);
                    const float ev[8] = {e0.x, e0.y, e0.z, e0.w, e1.x, e1.y, e1.z, e1.w};
                    union { unsigned u[4]; short8 s8; } af;
                    #pragma unroll
                    for (int jj = 0; jj < 4; ++jj) {
                        float r0 = __builtin_amdgcn_rcpf(fmaf(ev[2 * jj],     a, 1.0f));
                        float r1 = __builtin_amdgcn_rcpf(fmaf(ev[2 * jj + 1], a, 1.0f));
                        if (diag) {
                            const int s_ = kk * 32 + quad * 8 + 2 * jj;
                            if (s_     > row) r0 = 0.0f;
                            if (s_ + 1 > row) r1 = 0.0f;
                        }
                        af.u[jj] = __builtin_amdgcn_perm(__float_as_uint(r1),
                                                         __float_as_uint(r0), 0x07060302u);
                    }
                    #pragma unroll
                    for (int j = 0; j < 4; ++j) {
                        const short8 bfr = *(const short8*)
                            &Vd[sg][(16 * j + n) * 64 + (((kk * 4 + quad) ^ (n & 7)) << 3)];
                        acc[j] = __builtin_amdgcn_mfma_f32_16x16x32_bf16(af.s8, bfr, acc[j], 0, 0, 0);
                    }
                }
            }
        }

        __syncthreads();
        if (sg == 1) {
            #pragma unroll
            for (int j = 0; j < 4; ++j)
                #pragma unroll
                for (int r = 0; r < 4; ++r)
                    red[(j * 4 + r) * 256 + w4 * 64 + lane] = acc[j][r];
        }
        __syncthreads();
        if (sg == 0) {
            #pragma unroll
            for (int j = 0; j < 4; ++j)
                #pragma unroll
                for (int r = 0; r < 4; ++r) {
                    const float o = acc[j][r] + red[(j * 4 + r) * 256 + w4 * 64 + lane];
                    const int t = t0 + w4 * 16 + quad * 4 + r;
                    yb[((size_t)b * T_LEN + t) * C_DIM + h * HD + 16 * j + n] = f2bf(o * inv);
                }
        }
    }
}

// ---------------------------------------------------------------------------
// 128x64-tile fp32-out GEMM (proj: 512 blocks -> 2/CU). 4 waves 2x2, acc 4x2.
// ---------------------------------------------------------------------------
__global__ __launch_bounds__(256)
void gemm_bf16_nt2(const u16* __restrict__ A, const u16* __restrict__ B,
                   float* __restrict__ C, int M, int N, int K) {
    __shared__ u16 As[128 * 32];
    __shared__ u16 Bs[64 * 32];
    const int tid    = threadIdx.x;
    const int lane   = tid & 63;
    const int wave   = tid >> 6;
    const int row_in = lane & 15;
    const int quad   = lane >> 4;
    const int koff   = quad * 8;
    const int rw     = (wave & 1) * 64;
    const int cw     = (wave >> 1) * 32;
    const int row0   = blockIdx.y * 128;
    const int col0   = blockIdx.x * 64;

    floatx4 acc[4][2] = {};

    for (int k0 = 0; k0 < K; k0 += 32) {
        #pragma unroll
        for (int c = 0; c < 2; ++c) {
            const int l  = c * 256 + tid;
            const int r  = l >> 2;
            const int kc = l & 3;
            gload_lds16(A + (size_t)(row0 + r) * K + k0 + kc * 8, &As[(size_t)l * 8]);
        }
        {
            const int r  = tid >> 2;
            const int kc = tid & 3;
            gload_lds16(B + (size_t)(col0 + r) * K + k0 + kc * 8, &Bs[(size_t)tid * 8]);
        }
        __syncthreads();
        short8 af[4], bf_[2];
        #pragma unroll
        for (int i = 0; i < 4; ++i)
            af[i] = *(const short8*)&As[(rw + 16 * i + row_in) * 32 + koff];
        #pragma unroll
        for (int j = 0; j < 2; ++j)
            bf_[j] = *(const short8*)&Bs[(cw + 16 * j + row_in) * 32 + koff];
        #pragma unroll
        for (int i = 0; i < 4; ++i)
            #pragma unroll
            for (int j = 0; j < 2; ++j)
                acc[i][j] = __builtin_amdgcn_mfma_f32_16x16x32_bf16(af[i], bf_[j], acc[i][j], 0, 0, 0);
        __syncthreads();
    }

    #pragma unroll
    for (int i = 0; i < 4; ++i)
        #pragma unroll
        for (int j = 0; j < 2; ++j)
            #pragma unroll
            for (int r = 0; r < 4; ++r)
                C[(size_t)(row0 + rw + 16 * i + quad * 4 + r) * N + col0 + cw + 16 * j + row_in]
                    = acc[i][j][r];
}

// ---------------------------------------------------------------------------
extern "C" void kernel_launch(void* const* d_in, const int* in_sizes, int n_in,
                              void* d_out, int out_size, void* d_ws, size_t ws_size,
                              hipStream_t stream) {
    const float* x     = (const float*)d_in[0];
    const float* cosb  = (const float*)d_in[1];
    const float* sinb  = (const float*)d_in[2];
    const float* Wq    = (const float*)d_in[3];
    const float* Wk    = (const float*)d_in[4];
    const float* Wv    = (const float*)d_in[5];
    const float* Wproj = (const float*)d_in[6];
    const float* wb    = (const float*)d_in[7];
    float* out = (float*)d_out;

    char* w = (char*)d_ws;
    u16* xb     = (u16*)w;  w += (size_t)4096 * 1024 * 2;
    u16* Wqkvb  = (u16*)w;  w += (size_t)2048 * 1024 * 2;   // [Wq; Wk; Wv]
    u16* Wpb    = (u16*)w;  w += (size_t)1024 * 1024 * 2;
    u16* vb     = (u16*)w;  w += (size_t)4096 * 512 * 2;    // compact v bf16
    u16* yb     = (u16*)w;  w += (size_t)4096 * 1024 * 2;
    u16* VtB    = (u16*)w;  w += (size_t)BATCH * NKV * 64 * T_LEN * 2;
    float* esq  = (float*)w; w += (size_t)BATCH * NH * T_LEN * 4;
    float* esk  = (float*)w; w += (size_t)BATCH * NKV * T_LEN * 4;

    dim3 blk(256);
    cvt_all<<<7168, blk, 0, stream>>>(x, Wq, Wk, Wv, Wproj, xb, Wqkvb, Wpb);
    gemm_qkv<<<dim3(16, 32), blk, 0, stream>>>(xb, Wqkvb, vb, esq, esk, cosb, sinb, wb);
    vt_convert<<<512, blk, 0, stream>>>(vb, VtB);
    braid_attn<<<dim3(16, 32), dim3(512), 0, stream>>>(esq, esk, VtB, yb);
    gemm_bf16_nt2<<<dim3(16, 32), blk, 0, stream>>>(yb, Wpb, out, 4096, 1024, 1024);
}